// Round 12
// baseline (746.646 us; speedup 1.0000x reference)
//
#include <hip/hip_runtime.h>
#include <hip/hip_bf16.h>

typedef __hip_bfloat16 bf16;

#define NN 100000
#define NE 1600000
#define DD 64
#define NL 3
#define NG 128
#define BN_EPS 1e-5f
#define SCAN_BLK 98  // ceil(NN / 1024)
#define TILE_ROWS 64
#define NT ((NN + TILE_ROWS - 1) / TILE_ROWS)  // 1563
#define GB_NODES 49
#define GB_BLOCKS ((NN + GB_NODES - 1) / GB_NODES)  // 2041
#define ECAP 1536  // staged edges per block (mean 784, sd ~28)

// ---------------- dtype detect (int64 vs int32) ----------------
__global__ __launch_bounds__(256) void detect_kernel(const int* __restrict__ ei,
                                                     const int* __restrict__ batch,
                                                     int* __restrict__ flags) {
    __shared__ int s_e, s_b;
    if (threadIdx.x == 0) { s_e = 0; s_b = 0; }
    __syncthreads();
    for (int i = threadIdx.x; i < 512; i += 256) {
        if (ei[2 * i + 1] != 0) atomicOr(&s_e, 1);
        if (batch[NN - 1024 + 2 * i + 1] != 0) atomicOr(&s_b, 1);
    }
    __syncthreads();
    if (threadIdx.x == 0) { flags[0] = s_e; flags[1] = s_b; }  // 1 = int32, 0 = int64
}

__device__ __forceinline__ int ld_src(const int* ei, int e, int is32) {
    return is32 ? ei[e] : ei[2 * e];
}
__device__ __forceinline__ int ld_dst(const int* ei, int e, int is32) {
    return is32 ? ei[NE + e] : ei[2 * NE + 2 * e];
}
__device__ __forceinline__ int ld_batch(const int* b, int n, int is32) {
    return is32 ? b[n] : b[2 * n];
}
__device__ __forceinline__ float bflo(unsigned int v) {
    return __uint_as_float(v << 16);
}
__device__ __forceinline__ float bfhi(unsigned int v) {
    return __uint_as_float(v & 0xffff0000u);
}

// ---------------- degree (int) ----------------
__global__ __launch_bounds__(256) void deg_kernel(const int* __restrict__ ei,
                                                  const int* __restrict__ flags,
                                                  int* __restrict__ deg_cnt) {
    int is32 = flags[0];
    int e = blockIdx.x * 256 + threadIdx.x;
    if (e < NE) atomicAdd(&deg_cnt[ld_dst(ei, e, is32)], 1);
}

// ---------------- parallel exclusive scan of degrees -> rowptr (+ fused dinv) ----------------
__global__ __launch_bounds__(256) void scan_part_kernel(const int* __restrict__ deg_cnt,
                                                        int* __restrict__ blocksum,
                                                        float* __restrict__ dinv) {
    __shared__ int s[256];
    int base = blockIdx.x * 1024 + threadIdx.x * 4;
    int t = 0;
    if (base < NN) {  // NN % 4 == 0 -> whole int4 in-bounds
        int4 v = *(const int4*)(deg_cnt + base);
        t = v.x + v.y + v.z + v.w;
        float4 dv = make_float4(rsqrtf((float)v.x + 1.f), rsqrtf((float)v.y + 1.f),
                                rsqrtf((float)v.z + 1.f), rsqrtf((float)v.w + 1.f));
        *(float4*)(dinv + base) = dv;  // +1 self-loop
    }
    s[threadIdx.x] = t;
    __syncthreads();
    for (int off = 128; off > 0; off >>= 1) {
        if (threadIdx.x < off) s[threadIdx.x] += s[threadIdx.x + off];
        __syncthreads();
    }
    if (threadIdx.x == 0) blocksum[blockIdx.x] = s[0];
}

__global__ __launch_bounds__(128) void scan_mid_kernel(int* __restrict__ blocksum,
                                                       int* __restrict__ rowptr) {
    __shared__ int s[128];
    int tid = threadIdx.x;
    int v = (tid < SCAN_BLK) ? blocksum[tid] : 0;
    s[tid] = v;
    for (int off = 1; off < 128; off <<= 1) {
        __syncthreads();
        int a = (tid >= off) ? s[tid - off] : 0;
        __syncthreads();
        s[tid] += a;
    }
    __syncthreads();
    if (tid < SCAN_BLK) blocksum[tid] = s[tid] - v;  // exclusive
    if (tid == 127) rowptr[NN] = s[127];             // total == NE
}

__global__ __launch_bounds__(256) void scan_write_kernel(int* __restrict__ deg_cnt,
                                                         const int* __restrict__ blocksum,
                                                         int* __restrict__ rowptr) {
    __shared__ int s[256];
    int base = blockIdx.x * 1024 + threadIdx.x * 4;
    int4 v = make_int4(0, 0, 0, 0);
    if (base < NN) v = *(const int4*)(deg_cnt + base);
    int t = v.x + v.y + v.z + v.w;
    s[threadIdx.x] = t;
    for (int off = 1; off < 256; off <<= 1) {
        __syncthreads();
        int a = (threadIdx.x >= off) ? s[threadIdx.x - off] : 0;
        __syncthreads();
        s[threadIdx.x] += a;
    }
    __syncthreads();
    int pre = blocksum[blockIdx.x] + s[threadIdx.x] - t;  // exclusive prefix
    if (base < NN) {
        rowptr[base] = pre;
        rowptr[base + 1] = pre + v.x;
        rowptr[base + 2] = pre + v.x + v.y;
        rowptr[base + 3] = pre + v.x + v.y + v.z;
        *(int4*)(deg_cnt + base) = make_int4(0, 0, 0, 0);
    }
}

// ---------------- CSR fill: interleaved (src, weight) ----------------
__global__ __launch_bounds__(256) void fill_kernel(const int* __restrict__ ei,
                                                   const int* __restrict__ flags,
                                                   const float* __restrict__ dinv,
                                                   const int* __restrict__ rowptr,
                                                   int* __restrict__ cursor,
                                                   int2* __restrict__ csw) {
    int is32 = flags[0];
    int e = blockIdx.x * 256 + threadIdx.x;
    if (e >= NE) return;
    int s = ld_src(ei, e, is32), d = ld_dst(ei, e, is32);
    int pos = rowptr[d] + atomicAdd(&cursor[d], 1);
    float w = dinv[s] * dinv[d];
    csw[pos] = make_int2(s, __float_as_int(w));
}

// ---------------- LDS-tiled gemm: t_bf16 = act(BN(h)) @ W; BN stats inline ----------------
__global__ __launch_bounds__(256) void gemm_kernel(const float* __restrict__ h,
                                                   const float* __restrict__ W,
                                                   const float* __restrict__ accum_prev,
                                                   const float* __restrict__ gamma,
                                                   const float* __restrict__ beta,
                                                   int use_bn, float alpha,
                                                   bf16* __restrict__ t,
                                                   float* __restrict__ accum_l) {
    if (blockIdx.x == 0 && threadIdx.x < 128) accum_l[threadIdx.x] = 0.f;

    __shared__ float ls[TILE_ROWS * DD];  // 16 KB staged tile (post-activation)
    __shared__ float ssc[DD], ssh[DD];
    if (threadIdx.x < 64) {
        if (use_bn) {
            float S = accum_prev[threadIdx.x], Q = accum_prev[64 + threadIdx.x];
            float mean = S / (float)NN;
            float var = fmaxf(Q / (float)NN - mean * mean, 0.f);
            float sc = gamma[threadIdx.x] * rsqrtf(var + BN_EPS);
            ssc[threadIdx.x] = sc;
            ssh[threadIdx.x] = beta[threadIdx.x] - mean * sc;
        } else {
            ssc[threadIdx.x] = 1.f;
            ssh[threadIdx.x] = 0.f;
        }
    }

    int c = threadIdx.x & 63;
    int wv = threadIdx.x >> 6;  // wave id 0..3
    float w[DD];
#pragma unroll
    for (int k = 0; k < DD; ++k) w[k] = W[k * DD + c];
    __syncthreads();  // ssc/ssh ready

    for (int tile = blockIdx.x; tile < NT; tile += gridDim.x) {
        int row0 = tile * TILE_ROWS;
#pragma unroll
        for (int it = 0; it < 4; ++it) {
            int flat = (threadIdx.x + it * 256) * 4;  // 0..16380
            int gflat = row0 * DD + flat;
            if (gflat < NN * DD) {
                float4 hv = *(const float4*)(h + gflat);
                int c0 = flat & 63;
                float4 s4 = *(const float4*)(ssc + c0);
                float4 b4 = *(const float4*)(ssh + c0);
                float x0 = hv.x * s4.x + b4.x;
                float x1 = hv.y * s4.y + b4.y;
                float x2 = hv.z * s4.z + b4.z;
                float x3 = hv.w * s4.w + b4.w;
                x0 = fmaxf(x0, x0 * alpha);
                x1 = fmaxf(x1, x1 * alpha);
                x2 = fmaxf(x2, x2 * alpha);
                x3 = fmaxf(x3, x3 * alpha);
                *(float4*)(ls + flat) = make_float4(x0, x1, x2, x3);
            }
        }
        __syncthreads();
        int nrows = min(TILE_ROWS, NN - row0);
        int rend = min(wv * 16 + 16, nrows);
        for (int rl = wv * 16; rl < rend; ++rl) {
            const float4* hrow = (const float4*)(ls + rl * DD);
            float acc = 0.f;
#pragma unroll
            for (int kk = 0; kk < DD / 4; ++kk) {
                float4 hv = hrow[kk];  // wave-uniform LDS read -> broadcast
                acc += hv.x * w[4 * kk] + hv.y * w[4 * kk + 1] +
                       hv.z * w[4 * kk + 2] + hv.w * w[4 * kk + 3];
            }
            t[(size_t)(row0 + rl) * DD + c] = __float2bfloat16(acc);
        }
        __syncthreads();
    }
}

// ---------------- gather v4: 4 rows per wave-load ----------------
// Lane = (quarter q = lane>>4) x (feature-quad fo = lane&15). Each lane loads
// uint2 = 4 bf16 features; one instruction fetches FOUR neighbor rows. An
// 8-deep batch covers 32 edges (one latency window for 99.99% of nodes).
// Cross-quarter combine: shfl_xor 16/32. csw staged in LDS (dst-tiled).
__global__ __launch_bounds__(256) void gather_kernel(const bf16* __restrict__ t,
                                                     const float* __restrict__ dinv,
                                                     const float* __restrict__ bias,
                                                     const int* __restrict__ rowptr,
                                                     const int2* __restrict__ csw,
                                                     float* __restrict__ h,
                                                     float* __restrict__ accum_l) {
    __shared__ int2 se[ECAP];          // 12 KB staged (src, weight)
    __shared__ int srp[GB_NODES + 1];  // staged rowptr slice
    __shared__ float s_sum[4][64], s_sq[4][64];

    int lane = threadIdx.x & 63;
    int wv = threadIdx.x >> 6;
    int q = lane >> 4;    // quarter 0..3 (edge subslot)
    int fo = lane & 15;   // feature-quad 0..15 (features 4fo..4fo+3)
    int nb0 = blockIdx.x * GB_NODES;
    int nloc = min(GB_NODES, NN - nb0);

    for (int i = threadIdx.x; i <= nloc; i += 256) srp[i] = rowptr[nb0 + i];
    __syncthreads();
    int ebase = srp[0];
    int nE = srp[nloc] - ebase;
    int staged = (nE <= ECAP);
    int ncap = min(nE, ECAP);
    for (int i = threadIdx.x; i < ncap; i += 256) se[i] = csw[ebase + i];
    __syncthreads();

    const unsigned int* t2 = (const unsigned int*)t;  // 1 uint = 2 bf16
    float4 bb = ((const float4*)bias)[fo];
    float sum0 = 0.f, sum1 = 0.f, sum2 = 0.f, sum3 = 0.f;
    float sq0 = 0.f, sq1 = 0.f, sq2 = 0.f, sq3 = 0.f;

    for (int dl = wv; dl < nloc; dl += 4) {
        int d = nb0 + dl;
        float di = dinv[d];
        float dd = di * di;
        uint2 sv = *(const uint2*)(t2 + (size_t)d * 32 + fo * 2);
        float a0, a1, a2, a3;
        if (q == 0) {  // only quarter 0 carries self + bias (summed later)
            a0 = bflo(sv.x) * dd + bb.x;
            a1 = bfhi(sv.x) * dd + bb.y;
            a2 = bflo(sv.y) * dd + bb.z;
            a3 = bfhi(sv.y) * dd + bb.w;
        } else {
            a0 = a1 = a2 = a3 = 0.f;
        }
        int j = srp[dl] - ebase, jend = srp[dl + 1] - ebase;
        for (; j < jend; j += 32) {  // 8 instrs x 4 edges, masked tail
            float wgt[8];
            uint2 v[8];
#pragma unroll
            for (int u = 0; u < 8; ++u) {
                int e = j + 4 * u + q;
                bool valid = e < jend;
                int2 a;
                if (staged) a = se[valid ? e : 0];
                else a = csw[ebase + (valid ? e : 0)];
                wgt[u] = valid ? __int_as_float(a.y) : 0.f;
                v[u] = *(const uint2*)(t2 + (size_t)a.x * 32 + fo * 2);
            }
#pragma unroll
            for (int u = 0; u < 8; ++u) {
                a0 += bflo(v[u].x) * wgt[u];
                a1 += bfhi(v[u].x) * wgt[u];
                a2 += bflo(v[u].y) * wgt[u];
                a3 += bfhi(v[u].y) * wgt[u];
            }
        }
        // combine quarters
        a0 += __shfl_xor(a0, 16); a0 += __shfl_xor(a0, 32);
        a1 += __shfl_xor(a1, 16); a1 += __shfl_xor(a1, 32);
        a2 += __shfl_xor(a2, 16); a2 += __shfl_xor(a2, 32);
        a3 += __shfl_xor(a3, 16); a3 += __shfl_xor(a3, 32);
        if (q == 0) {
            ((float4*)(h + (size_t)d * DD))[fo] = make_float4(a0, a1, a2, a3);
            sum0 += a0; sq0 += a0 * a0;
            sum1 += a1; sq1 += a1 * a1;
            sum2 += a2; sq2 += a2 * a2;
            sum3 += a3; sq3 += a3 * a3;
        }
    }
    if (q == 0) {
        ((float4*)s_sum[wv])[fo] = make_float4(sum0, sum1, sum2, sum3);
        ((float4*)s_sq[wv])[fo] = make_float4(sq0, sq1, sq2, sq3);
    }
    __syncthreads();
    if (threadIdx.x < 64) {
        int f = threadIdx.x;
        float S = s_sum[0][f] + s_sum[1][f] + s_sum[2][f] + s_sum[3][f];
        float Q = s_sq[0][f] + s_sq[1][f] + s_sq[2][f] + s_sq[3][f];
        atomicAdd(&accum_l[f], S);
        atomicAdd(&accum_l[64 + f], Q);
    }
}

// ---------------- pool: inline BN finalize(layer3) + ReLU + mean-pool + counts ----------------
#define POOL_CHUNK 128
__global__ __launch_bounds__(256) void pool_kernel(const float* __restrict__ hraw,
                                                   const float* __restrict__ accum_l,
                                                   const float* __restrict__ gamma,
                                                   const float* __restrict__ beta,
                                                   const int* __restrict__ batch,
                                                   const int* __restrict__ flags,
                                                   float* __restrict__ pool,
                                                   float* __restrict__ counts) {
    __shared__ float ssc[64], ssh[64];
    if (threadIdx.x < 64) {
        float S = accum_l[threadIdx.x], Q = accum_l[64 + threadIdx.x];
        float mean = S / (float)NN;
        float var = fmaxf(Q / (float)NN - mean * mean, 0.f);
        float sc = gamma[threadIdx.x] * rsqrtf(var + BN_EPS);
        ssc[threadIdx.x] = sc;
        ssh[threadIdx.x] = beta[threadIdx.x] - mean * sc;
    }
    __syncthreads();
    int is32 = flags[1];
    int f = threadIdx.x & 63, rg = threadIdx.x >> 6;
    float sc = ssc[f], sh = ssh[f];
    int base = blockIdx.x * POOL_CHUNK;
    float acc = 0.f, cnt = 0.f;
    int cur = -1;
    for (int i = rg; i < POOL_CHUNK; i += 4) {
        int n = base + i;
        if (n >= NN) break;
        int g = ld_batch(batch, n, is32);
        if (g != cur) {
            if (cur >= 0) {
                atomicAdd(&pool[cur * DD + f], acc);
                if (f == 0) atomicAdd(&counts[cur], cnt);
            }
            acc = 0.f;
            cnt = 0.f;
            cur = g;
        }
        acc += fmaxf(hraw[(size_t)n * DD + f] * sc + sh, 0.f);
        cnt += 1.f;
    }
    if (cur >= 0) {
        atomicAdd(&pool[cur * DD + f], acc);
        if (f == 0) atomicAdd(&counts[cur], cnt);
    }
}

__global__ __launch_bounds__(256) void final_kernel(const float* __restrict__ pool,
                                                    const float* __restrict__ counts,
                                                    float* __restrict__ out) {
    int i = blockIdx.x * 256 + threadIdx.x;
    if (i < NG * DD) {
        int g = i >> 6;
        out[i] = pool[i] / fmaxf(counts[g], 1.0f);
    }
}

extern "C" void kernel_launch(void* const* d_in, const int* in_sizes, int n_in,
                              void* d_out, int out_size, void* d_ws, size_t ws_size,
                              hipStream_t stream) {
    const float* x = (const float*)d_in[0];       // [NN, DD] f32
    const int* edge_index = (const int*)d_in[1];  // [2, NE] int (width detected)
    const int* batch = (const int*)d_in[2];       // [NN] int (width detected)
    const float* Ws = (const float*)d_in[3];      // [3,64,64]
    const float* bs = (const float*)d_in[4];      // [3,64]
    const float* gammas = (const float*)d_in[5];  // [3,64]
    const float* betas = (const float*)d_in[6];   // [3,64]
    float* out = (float*)d_out;                   // [NG, DD]

    // workspace layout (csw 8B-aligned; deg_cnt/rowptr/dinv 16B-aligned)
    float* h = (float*)d_ws;                   // 6,400,000 f (raw agg per layer)
    bf16* t = (bf16*)(h + (size_t)NN * DD);    // 6,400,000 bf16 (12.8 MB)
    int2* csw = (int2*)(t + (size_t)NN * DD);  // NE int2 (12.8 MB)
    float* dinv = (float*)(csw + NE);          // 100,000 f
    int* deg_cnt = (int*)(dinv + NN);          // 100,000 i (also fill cursor)
    int* rowptr = deg_cnt + NN;                // 100,001 i
    float* accum = (float*)(rowptr + NN + 1);  // NL*128 f (BN sum/sumsq per layer)
    float* pool = accum + NL * 128;            // 8192 f
    float* counts = pool + NG * DD;            // 128 f
    int* flags = (int*)(counts + NG);          // 2 i
    int* blocksum = flags + 2;                 // 128 i

    hipMemsetAsync(deg_cnt, 0, NN * sizeof(int), stream);
    hipMemsetAsync(pool, 0, (NG * DD + NG) * sizeof(float), stream);

    detect_kernel<<<1, 256, 0, stream>>>(edge_index, batch, flags);
    deg_kernel<<<(NE + 255) / 256, 256, 0, stream>>>(edge_index, flags, deg_cnt);
    scan_part_kernel<<<SCAN_BLK, 256, 0, stream>>>(deg_cnt, blocksum, dinv);
    scan_mid_kernel<<<1, 128, 0, stream>>>(blocksum, rowptr);
    scan_write_kernel<<<SCAN_BLK, 256, 0, stream>>>(deg_cnt, blocksum, rowptr);
    fill_kernel<<<(NE + 255) / 256, 256, 0, stream>>>(edge_index, flags, dinv, rowptr,
                                                      deg_cnt, csw);

    for (int l = 0; l < NL; ++l) {
        const float* hin = (l == 0) ? x : h;
        float alpha = (l == 0) ? 1.0f : 0.0f;  // identity vs ReLU on input transform
        gemm_kernel<<<NT, 256, 0, stream>>>(hin, Ws + (size_t)l * DD * DD,
                                            accum + (l - 1 >= 0 ? l - 1 : 0) * 128,
                                            gammas + (l - 1 >= 0 ? l - 1 : 0) * DD,
                                            betas + (l - 1 >= 0 ? l - 1 : 0) * DD,
                                            (l > 0) ? 1 : 0, alpha, t, accum + l * 128);
        gather_kernel<<<GB_BLOCKS, 256, 0, stream>>>(t, dinv, bs + l * DD, rowptr, csw, h,
                                                     accum + l * 128);
    }

    pool_kernel<<<(NN + POOL_CHUNK - 1) / POOL_CHUNK, 256, 0, stream>>>(
        h, accum + 2 * 128, gammas + 2 * DD, betas + 2 * DD, batch, flags, pool, counts);
    final_kernel<<<(NG * DD + 255) / 256, 256, 0, stream>>>(pool, counts, out);
}

// Round 13
// 665.703 us; speedup vs baseline: 1.1216x; 1.1216x over previous
//
#include <hip/hip_runtime.h>
#include <hip/hip_bf16.h>

typedef __hip_bfloat16 bf16;

#define NN 100000
#define NE 1600000
#define DD 64
#define NL 3
#define NG 128
#define BN_EPS 1e-5f
#define SCAN_BLK 98  // ceil(NN / 1024)
#define TILE_ROWS 64
#define NT ((NN + TILE_ROWS - 1) / TILE_ROWS)  // 1563
#define GB_NODES 49
#define GB_BLOCKS ((NN + GB_NODES - 1) / GB_NODES)  // 2041
#define ECAP 1536  // staged edges per block (mean 784, sd ~28)

// ---------------- dtype detect (int64 vs int32) ----------------
__global__ __launch_bounds__(256) void detect_kernel(const int* __restrict__ ei,
                                                     const int* __restrict__ batch,
                                                     int* __restrict__ flags) {
    __shared__ int s_e, s_b;
    if (threadIdx.x == 0) { s_e = 0; s_b = 0; }
    __syncthreads();
    for (int i = threadIdx.x; i < 512; i += 256) {
        if (ei[2 * i + 1] != 0) atomicOr(&s_e, 1);
        if (batch[NN - 1024 + 2 * i + 1] != 0) atomicOr(&s_b, 1);
    }
    __syncthreads();
    if (threadIdx.x == 0) { flags[0] = s_e; flags[1] = s_b; }  // 1 = int32, 0 = int64
}

__device__ __forceinline__ int ld_src(const int* ei, int e, int is32) {
    return is32 ? ei[e] : ei[2 * e];
}
__device__ __forceinline__ int ld_dst(const int* ei, int e, int is32) {
    return is32 ? ei[NE + e] : ei[2 * NE + 2 * e];
}
__device__ __forceinline__ int ld_batch(const int* b, int n, int is32) {
    return is32 ? b[n] : b[2 * n];
}
__device__ __forceinline__ float bf2f(unsigned short u) {
    return __uint_as_float(((unsigned int)u) << 16);
}

// ---------------- degree (int) ----------------
__global__ __launch_bounds__(256) void deg_kernel(const int* __restrict__ ei,
                                                  const int* __restrict__ flags,
                                                  int* __restrict__ deg_cnt) {
    int is32 = flags[0];
    int e = blockIdx.x * 256 + threadIdx.x;
    if (e < NE) atomicAdd(&deg_cnt[ld_dst(ei, e, is32)], 1);
}

// ---------------- parallel exclusive scan of degrees -> rowptr (+ fused dinv) ----------------
__global__ __launch_bounds__(256) void scan_part_kernel(const int* __restrict__ deg_cnt,
                                                        int* __restrict__ blocksum,
                                                        float* __restrict__ dinv) {
    __shared__ int s[256];
    int base = blockIdx.x * 1024 + threadIdx.x * 4;
    int t = 0;
    if (base < NN) {  // NN % 4 == 0 -> whole int4 in-bounds
        int4 v = *(const int4*)(deg_cnt + base);
        t = v.x + v.y + v.z + v.w;
        float4 dv = make_float4(rsqrtf((float)v.x + 1.f), rsqrtf((float)v.y + 1.f),
                                rsqrtf((float)v.z + 1.f), rsqrtf((float)v.w + 1.f));
        *(float4*)(dinv + base) = dv;  // +1 self-loop
    }
    s[threadIdx.x] = t;
    __syncthreads();
    for (int off = 128; off > 0; off >>= 1) {
        if (threadIdx.x < off) s[threadIdx.x] += s[threadIdx.x + off];
        __syncthreads();
    }
    if (threadIdx.x == 0) blocksum[blockIdx.x] = s[0];
}

__global__ __launch_bounds__(128) void scan_mid_kernel(int* __restrict__ blocksum,
                                                       int* __restrict__ rowptr) {
    __shared__ int s[128];
    int tid = threadIdx.x;
    int v = (tid < SCAN_BLK) ? blocksum[tid] : 0;
    s[tid] = v;
    for (int off = 1; off < 128; off <<= 1) {
        __syncthreads();
        int a = (tid >= off) ? s[tid - off] : 0;
        __syncthreads();
        s[tid] += a;
    }
    __syncthreads();
    if (tid < SCAN_BLK) blocksum[tid] = s[tid] - v;  // exclusive
    if (tid == 127) rowptr[NN] = s[127];             // total == NE
}

__global__ __launch_bounds__(256) void scan_write_kernel(int* __restrict__ deg_cnt,
                                                         const int* __restrict__ blocksum,
                                                         int* __restrict__ rowptr) {
    __shared__ int s[256];
    int base = blockIdx.x * 1024 + threadIdx.x * 4;
    int4 v = make_int4(0, 0, 0, 0);
    if (base < NN) v = *(const int4*)(deg_cnt + base);
    int t = v.x + v.y + v.z + v.w;
    s[threadIdx.x] = t;
    for (int off = 1; off < 256; off <<= 1) {
        __syncthreads();
        int a = (threadIdx.x >= off) ? s[threadIdx.x - off] : 0;
        __syncthreads();
        s[threadIdx.x] += a;
    }
    __syncthreads();
    int pre = blocksum[blockIdx.x] + s[threadIdx.x] - t;  // exclusive prefix
    if (base < NN) {
        rowptr[base] = pre;
        rowptr[base + 1] = pre + v.x;
        rowptr[base + 2] = pre + v.x + v.y;
        rowptr[base + 3] = pre + v.x + v.y + v.z;
        *(int4*)(deg_cnt + base) = make_int4(0, 0, 0, 0);
    }
}

// ---------------- CSR fill: interleaved (src, weight) ----------------
__global__ __launch_bounds__(256) void fill_kernel(const int* __restrict__ ei,
                                                   const int* __restrict__ flags,
                                                   const float* __restrict__ dinv,
                                                   const int* __restrict__ rowptr,
                                                   int* __restrict__ cursor,
                                                   int2* __restrict__ csw) {
    int is32 = flags[0];
    int e = blockIdx.x * 256 + threadIdx.x;
    if (e >= NE) return;
    int s = ld_src(ei, e, is32), d = ld_dst(ei, e, is32);
    int pos = rowptr[d] + atomicAdd(&cursor[d], 1);
    float w = dinv[s] * dinv[d];
    csw[pos] = make_int2(s, __float_as_int(w));
}

// ---------------- LDS-tiled gemm: t_bf16 = act(BN(h)) @ W; BN stats inline ----------------
__global__ __launch_bounds__(256) void gemm_kernel(const float* __restrict__ h,
                                                   const float* __restrict__ W,
                                                   const float* __restrict__ accum_prev,
                                                   const float* __restrict__ gamma,
                                                   const float* __restrict__ beta,
                                                   int use_bn, float alpha,
                                                   bf16* __restrict__ t,
                                                   float* __restrict__ accum_l) {
    if (blockIdx.x == 0 && threadIdx.x < 128) accum_l[threadIdx.x] = 0.f;

    __shared__ float ls[TILE_ROWS * DD];  // 16 KB staged tile (post-activation)
    __shared__ float ssc[DD], ssh[DD];
    if (threadIdx.x < 64) {
        if (use_bn) {
            float S = accum_prev[threadIdx.x], Q = accum_prev[64 + threadIdx.x];
            float mean = S / (float)NN;
            float var = fmaxf(Q / (float)NN - mean * mean, 0.f);
            float sc = gamma[threadIdx.x] * rsqrtf(var + BN_EPS);
            ssc[threadIdx.x] = sc;
            ssh[threadIdx.x] = beta[threadIdx.x] - mean * sc;
        } else {
            ssc[threadIdx.x] = 1.f;
            ssh[threadIdx.x] = 0.f;
        }
    }

    int c = threadIdx.x & 63;
    int wv = threadIdx.x >> 6;  // wave id 0..3
    float w[DD];
#pragma unroll
    for (int k = 0; k < DD; ++k) w[k] = W[k * DD + c];
    __syncthreads();  // ssc/ssh ready

    for (int tile = blockIdx.x; tile < NT; tile += gridDim.x) {
        int row0 = tile * TILE_ROWS;
#pragma unroll
        for (int it = 0; it < 4; ++it) {
            int flat = (threadIdx.x + it * 256) * 4;  // 0..16380
            int gflat = row0 * DD + flat;
            if (gflat < NN * DD) {
                float4 hv = *(const float4*)(h + gflat);
                int c0 = flat & 63;
                float4 s4 = *(const float4*)(ssc + c0);
                float4 b4 = *(const float4*)(ssh + c0);
                float x0 = hv.x * s4.x + b4.x;
                float x1 = hv.y * s4.y + b4.y;
                float x2 = hv.z * s4.z + b4.z;
                float x3 = hv.w * s4.w + b4.w;
                x0 = fmaxf(x0, x0 * alpha);
                x1 = fmaxf(x1, x1 * alpha);
                x2 = fmaxf(x2, x2 * alpha);
                x3 = fmaxf(x3, x3 * alpha);
                *(float4*)(ls + flat) = make_float4(x0, x1, x2, x3);
            }
        }
        __syncthreads();
        int nrows = min(TILE_ROWS, NN - row0);
        int rend = min(wv * 16 + 16, nrows);
        for (int rl = wv * 16; rl < rend; ++rl) {
            const float4* hrow = (const float4*)(ls + rl * DD);
            float acc = 0.f;
#pragma unroll
            for (int kk = 0; kk < DD / 4; ++kk) {
                float4 hv = hrow[kk];  // wave-uniform LDS read -> broadcast
                acc += hv.x * w[4 * kk] + hv.y * w[4 * kk + 1] +
                       hv.z * w[4 * kk + 2] + hv.w * w[4 * kk + 3];
            }
            t[(size_t)(row0 + rl) * DD + c] = __float2bfloat16(acc);
        }
        __syncthreads();
    }
}

// ---------------- gather v5: dst-tiled, csw in LDS, TWO nodes pipelined per wave ----------------
// Per iteration a wave issues node A's 8 neighbor-row loads AND node B's 8
// before consuming either -> 16 lines in flight, one shared latency window.
// 1 feature/lane (1 cache line per wave-load instruction, conflict-free).
__global__ __launch_bounds__(256) void gather_kernel(const bf16* __restrict__ t,
                                                     const float* __restrict__ dinv,
                                                     const float* __restrict__ bias,
                                                     const int* __restrict__ rowptr,
                                                     const int2* __restrict__ csw,
                                                     float* __restrict__ h,
                                                     float* __restrict__ accum_l) {
    __shared__ int2 se[ECAP];          // 12 KB staged (src, weight)
    __shared__ int srp[GB_NODES + 1];  // staged rowptr slice
    __shared__ float s_sum[256], s_sq[256];

    int f = threadIdx.x & 63;
    int wv = threadIdx.x >> 6;
    int nb0 = blockIdx.x * GB_NODES;
    int nloc = min(GB_NODES, NN - nb0);

    for (int i = threadIdx.x; i <= nloc; i += 256) srp[i] = rowptr[nb0 + i];
    __syncthreads();
    int ebase = srp[0];
    int nE = srp[nloc] - ebase;
    bool staged = (nE <= ECAP);
    int ncap = min(nE, ECAP);
    for (int i = threadIdx.x; i < ncap; i += 256) se[i] = csw[ebase + i];
    __syncthreads();

    const unsigned short* tf = (const unsigned short*)t + f;  // lane-fixed feature ptr
    float bb = bias[f];
    float sum = 0.f, sq = 0.f;

    for (int p = wv; 2 * p < nloc; p += 4) {  // wave handles node pair (2p, 2p+1)
        int dlA = 2 * p, dlB = 2 * p + 1;
        int dA = nb0 + dlA;
        bool hasB = dlB < nloc;
        int dB = hasB ? nb0 + dlB : dA;
        float diA = dinv[dA], diB = dinv[dB];
        float accA = bf2f(tf[(size_t)dA * DD]) * diA * diA + bb;
        float accB = hasB ? (bf2f(tf[(size_t)dB * DD]) * diB * diB + bb) : 0.f;
        int jA = srp[dlA] - ebase, jendA = srp[dlA + 1] - ebase;
        int jB = hasB ? jendA : 0, jendB = hasB ? (srp[dlB + 1] - ebase) : 0;

        if (staged) {
            while (jA < jendA || jB < jendB) {
                int2 aA[8], aB[8];
                unsigned short rA[8], rB[8];
#pragma unroll
                for (int u = 0; u < 8; ++u) {
                    aA[u] = se[(jA + u < jendA) ? (jA + u) : 0];
                    aB[u] = se[(jB + u < jendB) ? (jB + u) : 0];
                }
#pragma unroll
                for (int u = 0; u < 8; ++u) {
                    rA[u] = tf[(size_t)aA[u].x * DD];
                    rB[u] = tf[(size_t)aB[u].x * DD];
                }
#pragma unroll
                for (int u = 0; u < 8; ++u) {
                    if (jA + u < jendA) accA += bf2f(rA[u]) * __int_as_float(aA[u].y);
                    if (jB + u < jendB) accB += bf2f(rB[u]) * __int_as_float(aB[u].y);
                }
                jA = min(jA + 8, jendA);
                jB = min(jB + 8, jendB);
            }
        } else {  // overflow block (vanishingly rare): csw from global
            while (jA < jendA || jB < jendB) {
                int2 aA[8], aB[8];
                unsigned short rA[8], rB[8];
#pragma unroll
                for (int u = 0; u < 8; ++u) {
                    aA[u] = csw[ebase + ((jA + u < jendA) ? (jA + u) : 0)];
                    aB[u] = csw[ebase + ((jB + u < jendB) ? (jB + u) : 0)];
                }
#pragma unroll
                for (int u = 0; u < 8; ++u) {
                    rA[u] = tf[(size_t)aA[u].x * DD];
                    rB[u] = tf[(size_t)aB[u].x * DD];
                }
#pragma unroll
                for (int u = 0; u < 8; ++u) {
                    if (jA + u < jendA) accA += bf2f(rA[u]) * __int_as_float(aA[u].y);
                    if (jB + u < jendB) accB += bf2f(rB[u]) * __int_as_float(aB[u].y);
                }
                jA = min(jA + 8, jendA);
                jB = min(jB + 8, jendB);
            }
        }
        h[(size_t)dA * DD + f] = accA;
        sum += accA;
        sq += accA * accA;
        if (hasB) {
            h[(size_t)dB * DD + f] = accB;
            sum += accB;
            sq += accB * accB;
        }
    }
    s_sum[threadIdx.x] = sum;
    s_sq[threadIdx.x] = sq;
    __syncthreads();
    if (threadIdx.x < 64) {
        sum = s_sum[f] + s_sum[64 + f] + s_sum[128 + f] + s_sum[192 + f];
        sq = s_sq[f] + s_sq[64 + f] + s_sq[128 + f] + s_sq[192 + f];
        atomicAdd(&accum_l[f], sum);
        atomicAdd(&accum_l[64 + f], sq);
    }
}

// ---------------- pool: inline BN finalize(layer3) + ReLU + mean-pool + counts ----------------
#define POOL_CHUNK 128
__global__ __launch_bounds__(256) void pool_kernel(const float* __restrict__ hraw,
                                                   const float* __restrict__ accum_l,
                                                   const float* __restrict__ gamma,
                                                   const float* __restrict__ beta,
                                                   const int* __restrict__ batch,
                                                   const int* __restrict__ flags,
                                                   float* __restrict__ pool,
                                                   float* __restrict__ counts) {
    __shared__ float ssc[64], ssh[64];
    if (threadIdx.x < 64) {
        float S = accum_l[threadIdx.x], Q = accum_l[64 + threadIdx.x];
        float mean = S / (float)NN;
        float var = fmaxf(Q / (float)NN - mean * mean, 0.f);
        float sc = gamma[threadIdx.x] * rsqrtf(var + BN_EPS);
        ssc[threadIdx.x] = sc;
        ssh[threadIdx.x] = beta[threadIdx.x] - mean * sc;
    }
    __syncthreads();
    int is32 = flags[1];
    int f = threadIdx.x & 63, rg = threadIdx.x >> 6;
    float sc = ssc[f], sh = ssh[f];
    int base = blockIdx.x * POOL_CHUNK;
    float acc = 0.f, cnt = 0.f;
    int cur = -1;
    for (int i = rg; i < POOL_CHUNK; i += 4) {
        int n = base + i;
        if (n >= NN) break;
        int g = ld_batch(batch, n, is32);
        if (g != cur) {
            if (cur >= 0) {
                atomicAdd(&pool[cur * DD + f], acc);
                if (f == 0) atomicAdd(&counts[cur], cnt);
            }
            acc = 0.f;
            cnt = 0.f;
            cur = g;
        }
        acc += fmaxf(hraw[(size_t)n * DD + f] * sc + sh, 0.f);
        cnt += 1.f;
    }
    if (cur >= 0) {
        atomicAdd(&pool[cur * DD + f], acc);
        if (f == 0) atomicAdd(&counts[cur], cnt);
    }
}

__global__ __launch_bounds__(256) void final_kernel(const float* __restrict__ pool,
                                                    const float* __restrict__ counts,
                                                    float* __restrict__ out) {
    int i = blockIdx.x * 256 + threadIdx.x;
    if (i < NG * DD) {
        int g = i >> 6;
        out[i] = pool[i] / fmaxf(counts[g], 1.0f);
    }
}

extern "C" void kernel_launch(void* const* d_in, const int* in_sizes, int n_in,
                              void* d_out, int out_size, void* d_ws, size_t ws_size,
                              hipStream_t stream) {
    const float* x = (const float*)d_in[0];       // [NN, DD] f32
    const int* edge_index = (const int*)d_in[1];  // [2, NE] int (width detected)
    const int* batch = (const int*)d_in[2];       // [NN] int (width detected)
    const float* Ws = (const float*)d_in[3];      // [3,64,64]
    const float* bs = (const float*)d_in[4];      // [3,64]
    const float* gammas = (const float*)d_in[5];  // [3,64]
    const float* betas = (const float*)d_in[6];   // [3,64]
    float* out = (float*)d_out;                   // [NG, DD]

    // workspace layout (csw 8B-aligned; deg_cnt/rowptr/dinv 16B-aligned)
    float* h = (float*)d_ws;                   // 6,400,000 f (raw agg per layer)
    bf16* t = (bf16*)(h + (size_t)NN * DD);    // 6,400,000 bf16 (12.8 MB)
    int2* csw = (int2*)(t + (size_t)NN * DD);  // NE int2 (12.8 MB)
    float* dinv = (float*)(csw + NE);          // 100,000 f
    int* deg_cnt = (int*)(dinv + NN);          // 100,000 i (also fill cursor)
    int* rowptr = deg_cnt + NN;                // 100,001 i
    float* accum = (float*)(rowptr + NN + 1);  // NL*128 f (BN sum/sumsq per layer)
    float* pool = accum + NL * 128;            // 8192 f
    float* counts = pool + NG * DD;            // 128 f
    int* flags = (int*)(counts + NG);          // 2 i
    int* blocksum = flags + 2;                 // 128 i

    hipMemsetAsync(deg_cnt, 0, NN * sizeof(int), stream);
    hipMemsetAsync(pool, 0, (NG * DD + NG) * sizeof(float), stream);

    detect_kernel<<<1, 256, 0, stream>>>(edge_index, batch, flags);
    deg_kernel<<<(NE + 255) / 256, 256, 0, stream>>>(edge_index, flags, deg_cnt);
    scan_part_kernel<<<SCAN_BLK, 256, 0, stream>>>(deg_cnt, blocksum, dinv);
    scan_mid_kernel<<<1, 128, 0, stream>>>(blocksum, rowptr);
    scan_write_kernel<<<SCAN_BLK, 256, 0, stream>>>(deg_cnt, blocksum, rowptr);
    fill_kernel<<<(NE + 255) / 256, 256, 0, stream>>>(edge_index, flags, dinv, rowptr,
                                                      deg_cnt, csw);

    for (int l = 0; l < NL; ++l) {
        const float* hin = (l == 0) ? x : h;
        float alpha = (l == 0) ? 1.0f : 0.0f;  // identity vs ReLU on input transform
        gemm_kernel<<<NT, 256, 0, stream>>>(hin, Ws + (size_t)l * DD * DD,
                                            accum + (l - 1 >= 0 ? l - 1 : 0) * 128,
                                            gammas + (l - 1 >= 0 ? l - 1 : 0) * DD,
                                            betas + (l - 1 >= 0 ? l - 1 : 0) * DD,
                                            (l > 0) ? 1 : 0, alpha, t, accum + l * 128);
        gather_kernel<<<GB_BLOCKS, 256, 0, stream>>>(t, dinv, bs + l * DD, rowptr, csw, h,
                                                     accum + l * 128);
    }

    pool_kernel<<<(NN + POOL_CHUNK - 1) / POOL_CHUNK, 256, 0, stream>>>(
        h, accum + 2 * 128, gammas + 2 * DD, betas + 2 * DD, batch, flags, pool, counts);
    final_kernel<<<(NG * DD + 255) / 256, 256, 0, stream>>>(pool, counts, out);
}

// Round 14
// 649.549 us; speedup vs baseline: 1.1495x; 1.0249x over previous
//
#include <hip/hip_runtime.h>
#include <hip/hip_bf16.h>

typedef __hip_bfloat16 bf16;

#define NN 100000
#define NE 1600000
#define DD 64
#define NL 3
#define NG 128
#define BN_EPS 1e-5f
#define SCAN_BLK 98  // ceil(NN / 1024)
#define TILE_ROWS 64
#define NT ((NN + TILE_ROWS - 1) / TILE_ROWS)  // 1563
#define GB_NODES 49
#define GB_BLOCKS ((NN + GB_NODES - 1) / GB_NODES)  // 2041
#define ECAP 1664    // staged padded edges per block (mean ~955)
#define CSW_CAP (NE + 7 * NN)  // padded CSR worst case

// ---------------- dtype detect (int64 vs int32) ----------------
__global__ __launch_bounds__(256) void detect_kernel(const int* __restrict__ ei,
                                                     const int* __restrict__ batch,
                                                     int* __restrict__ flags) {
    __shared__ int s_e, s_b;
    if (threadIdx.x == 0) { s_e = 0; s_b = 0; }
    __syncthreads();
    for (int i = threadIdx.x; i < 512; i += 256) {
        if (ei[2 * i + 1] != 0) atomicOr(&s_e, 1);
        if (batch[NN - 1024 + 2 * i + 1] != 0) atomicOr(&s_b, 1);
    }
    __syncthreads();
    if (threadIdx.x == 0) { flags[0] = s_e; flags[1] = s_b; }  // 1 = int32, 0 = int64
}

__device__ __forceinline__ int ld_src(const int* ei, int e, int is32) {
    return is32 ? ei[e] : ei[2 * e];
}
__device__ __forceinline__ int ld_dst(const int* ei, int e, int is32) {
    return is32 ? ei[NE + e] : ei[2 * NE + 2 * e];
}
__device__ __forceinline__ int ld_batch(const int* b, int n, int is32) {
    return is32 ? b[n] : b[2 * n];
}
__device__ __forceinline__ float bf2f(unsigned short u) {
    return __uint_as_float(((unsigned int)u) << 16);
}
__device__ __forceinline__ int pad8(int d) { return (d + 7) & ~7; }

// ---------------- degree (int) ----------------
__global__ __launch_bounds__(256) void deg_kernel(const int* __restrict__ ei,
                                                  const int* __restrict__ flags,
                                                  int* __restrict__ deg_cnt) {
    int is32 = flags[0];
    int e = blockIdx.x * 256 + threadIdx.x;
    if (e < NE) atomicAdd(&deg_cnt[ld_dst(ei, e, is32)], 1);
}

// ---------------- scan phase 1: per-block PADDED-degree totals (+ fused dinv) ----------------
__global__ __launch_bounds__(256) void scan_part_kernel(const int* __restrict__ deg_cnt,
                                                        int* __restrict__ blocksum,
                                                        float* __restrict__ dinv) {
    __shared__ int s[256];
    int base = blockIdx.x * 1024 + threadIdx.x * 4;
    int t = 0;
    if (base < NN) {  // NN % 4 == 0 -> whole int4 in-bounds
        int4 v = *(const int4*)(deg_cnt + base);
        t = pad8(v.x) + pad8(v.y) + pad8(v.z) + pad8(v.w);
        float4 dv = make_float4(rsqrtf((float)v.x + 1.f), rsqrtf((float)v.y + 1.f),
                                rsqrtf((float)v.z + 1.f), rsqrtf((float)v.w + 1.f));
        *(float4*)(dinv + base) = dv;  // +1 self-loop
    }
    s[threadIdx.x] = t;
    __syncthreads();
    for (int off = 128; off > 0; off >>= 1) {
        if (threadIdx.x < off) s[threadIdx.x] += s[threadIdx.x + off];
        __syncthreads();
    }
    if (threadIdx.x == 0) blocksum[blockIdx.x] = s[0];
}

// ---------------- scan phase 2: each block re-scans block sums + writes rowptr (padded) ----------------
__global__ __launch_bounds__(256) void scan_write_kernel(int* __restrict__ deg_cnt,
                                                         const int* __restrict__ blocksum,
                                                         int* __restrict__ rowptr) {
    __shared__ int sb[128];
    __shared__ int s[256];
    if (threadIdx.x < 128)
        sb[threadIdx.x] = (threadIdx.x < SCAN_BLK) ? blocksum[threadIdx.x] : 0;
    __syncthreads();
    for (int off = 1; off < 128; off <<= 1) {
        int a = 0;
        if (threadIdx.x < 128 && threadIdx.x >= off) a = sb[threadIdx.x - off];
        __syncthreads();
        if (threadIdx.x < 128) sb[threadIdx.x] += a;
        __syncthreads();
    }
    int blockpre = (blockIdx.x == 0) ? 0 : sb[blockIdx.x - 1];
    if (blockIdx.x == SCAN_BLK - 1 && threadIdx.x == 0)
        rowptr[NN] = sb[SCAN_BLK - 1];  // padded total

    int base = blockIdx.x * 1024 + threadIdx.x * 4;
    int4 v = make_int4(0, 0, 0, 0);
    if (base < NN) v = *(const int4*)(deg_cnt + base);
    int p0 = pad8(v.x), p1 = pad8(v.y), p2 = pad8(v.z), p3 = pad8(v.w);
    int t = p0 + p1 + p2 + p3;
    s[threadIdx.x] = t;
    for (int off = 1; off < 256; off <<= 1) {
        __syncthreads();
        int a = (threadIdx.x >= off) ? s[threadIdx.x - off] : 0;
        __syncthreads();
        s[threadIdx.x] += a;
    }
    __syncthreads();
    int pre = blockpre + s[threadIdx.x] - t;  // exclusive padded prefix
    if (base < NN) {
        rowptr[base] = pre;
        rowptr[base + 1] = pre + p0;
        rowptr[base + 2] = pre + p0 + p1;
        rowptr[base + 3] = pre + p0 + p1 + p2;
        *(int4*)(deg_cnt + base) = make_int4(0, 0, 0, 0);
    }
}

// ---------------- CSR fill: (pre-scaled byte offset, weight); pads stay zero ----------------
__global__ __launch_bounds__(256) void fill_kernel(const int* __restrict__ ei,
                                                   const int* __restrict__ flags,
                                                   const float* __restrict__ dinv,
                                                   const int* __restrict__ rowptr,
                                                   int* __restrict__ cursor,
                                                   int2* __restrict__ csw) {
    int is32 = flags[0];
    int e = blockIdx.x * 256 + threadIdx.x;
    if (e >= NE) return;
    int s = ld_src(ei, e, is32), d = ld_dst(ei, e, is32);
    int pos = rowptr[d] + atomicAdd(&cursor[d], 1);
    float w = dinv[s] * dinv[d];
    csw[pos] = make_int2(s << 7, __float_as_int(w));  // s * DD * sizeof(bf16) = s*128
}

// ---------------- LDS-tiled gemm: t_bf16 = act(BN(h)) @ W; BN stats inline ----------------
__global__ __launch_bounds__(256) void gemm_kernel(const float* __restrict__ h,
                                                   const float* __restrict__ W,
                                                   const float* __restrict__ accum_prev,
                                                   const float* __restrict__ gamma,
                                                   const float* __restrict__ beta,
                                                   int use_bn, float alpha,
                                                   bf16* __restrict__ t,
                                                   float* __restrict__ accum_l) {
    if (blockIdx.x == 0 && threadIdx.x < 128) accum_l[threadIdx.x] = 0.f;

    __shared__ float ls[TILE_ROWS * DD];  // 16 KB staged tile (post-activation)
    __shared__ float ssc[DD], ssh[DD];
    if (threadIdx.x < 64) {
        if (use_bn) {
            float S = accum_prev[threadIdx.x], Q = accum_prev[64 + threadIdx.x];
            float mean = S / (float)NN;
            float var = fmaxf(Q / (float)NN - mean * mean, 0.f);
            float sc = gamma[threadIdx.x] * rsqrtf(var + BN_EPS);
            ssc[threadIdx.x] = sc;
            ssh[threadIdx.x] = beta[threadIdx.x] - mean * sc;
        } else {
            ssc[threadIdx.x] = 1.f;
            ssh[threadIdx.x] = 0.f;
        }
    }

    int c = threadIdx.x & 63;
    int wv = threadIdx.x >> 6;  // wave id 0..3
    float w[DD];
#pragma unroll
    for (int k = 0; k < DD; ++k) w[k] = W[k * DD + c];
    __syncthreads();  // ssc/ssh ready

    for (int tile = blockIdx.x; tile < NT; tile += gridDim.x) {
        int row0 = tile * TILE_ROWS;
#pragma unroll
        for (int it = 0; it < 4; ++it) {
            int flat = (threadIdx.x + it * 256) * 4;  // 0..16380
            int gflat = row0 * DD + flat;
            if (gflat < NN * DD) {
                float4 hv = *(const float4*)(h + gflat);
                int c0 = flat & 63;
                float4 s4 = *(const float4*)(ssc + c0);
                float4 b4 = *(const float4*)(ssh + c0);
                float x0 = hv.x * s4.x + b4.x;
                float x1 = hv.y * s4.y + b4.y;
                float x2 = hv.z * s4.z + b4.z;
                float x3 = hv.w * s4.w + b4.w;
                x0 = fmaxf(x0, x0 * alpha);
                x1 = fmaxf(x1, x1 * alpha);
                x2 = fmaxf(x2, x2 * alpha);
                x3 = fmaxf(x3, x3 * alpha);
                *(float4*)(ls + flat) = make_float4(x0, x1, x2, x3);
            }
        }
        __syncthreads();
        int nrows = min(TILE_ROWS, NN - row0);
        int rend = min(wv * 16 + 16, nrows);
        for (int rl = wv * 16; rl < rend; ++rl) {
            const float4* hrow = (const float4*)(ls + rl * DD);
            float acc = 0.f;
#pragma unroll
            for (int kk = 0; kk < DD / 4; ++kk) {
                float4 hv = hrow[kk];  // wave-uniform LDS read -> broadcast
                acc += hv.x * w[4 * kk] + hv.y * w[4 * kk + 1] +
                       hv.z * w[4 * kk + 2] + hv.w * w[4 * kk + 3];
            }
            t[(size_t)(row0 + rl) * DD + c] = __float2bfloat16(acc);
        }
        __syncthreads();
    }
}

// ---------------- gather v6: padded CSR -> zero masking; dual-node pipeline ----------------
__device__ __forceinline__ void batch8(const int2* __restrict__ ep, int j,
                                       const char* __restrict__ tbase, int f2,
                                       float& acc) {
    int2 a[8];
    unsigned short r[8];
#pragma unroll
    for (int u = 0; u < 8; ++u) a[u] = ep[j + u];
#pragma unroll
    for (int u = 0; u < 8; ++u)
        r[u] = *(const unsigned short*)(tbase + (unsigned)(a[u].x + f2));
#pragma unroll
    for (int u = 0; u < 8; ++u) acc += bf2f(r[u]) * __int_as_float(a[u].y);
}

__device__ __forceinline__ void batch8x2(const int2* __restrict__ ep, int jA, int jB,
                                         const char* __restrict__ tbase, int f2,
                                         float& accA, float& accB) {
    int2 aA[8], aB[8];
    unsigned short rA[8], rB[8];
#pragma unroll
    for (int u = 0; u < 8; ++u) { aA[u] = ep[jA + u]; aB[u] = ep[jB + u]; }
#pragma unroll
    for (int u = 0; u < 8; ++u) {
        rA[u] = *(const unsigned short*)(tbase + (unsigned)(aA[u].x + f2));
        rB[u] = *(const unsigned short*)(tbase + (unsigned)(aB[u].x + f2));
    }
#pragma unroll
    for (int u = 0; u < 8; ++u) {
        accA += bf2f(rA[u]) * __int_as_float(aA[u].y);
        accB += bf2f(rB[u]) * __int_as_float(aB[u].y);
    }
}

__global__ __launch_bounds__(256) void gather_kernel(const bf16* __restrict__ t,
                                                     const float* __restrict__ dinv,
                                                     const float* __restrict__ bias,
                                                     const int* __restrict__ rowptr,
                                                     const int2* __restrict__ csw,
                                                     float* __restrict__ h,
                                                     float* __restrict__ accum_l) {
    __shared__ int2 se[ECAP];          // 13 KB staged (byte-offset, weight)
    __shared__ int srp[GB_NODES + 1];  // staged rowptr slice
    __shared__ float s_sum[256], s_sq[256];

    int f = threadIdx.x & 63;
    int wv = threadIdx.x >> 6;
    int nb0 = blockIdx.x * GB_NODES;
    int nloc = min(GB_NODES, NN - nb0);

    for (int i = threadIdx.x; i <= nloc; i += 256) srp[i] = rowptr[nb0 + i];
    __syncthreads();
    int ebase = srp[0];
    int nE = srp[nloc] - ebase;
    bool staged = (nE <= ECAP);
    int ncap = min(nE, ECAP);
    for (int i = threadIdx.x; i < ncap; i += 256) se[i] = csw[ebase + i];
    __syncthreads();

    const char* tbase = (const char*)t;
    int f2 = f * 2;
    const unsigned short* tf = (const unsigned short*)t + f;
    float bb = bias[f];
    float sum = 0.f, sq = 0.f;

    for (int p = wv; 2 * p < nloc; p += 4) {  // wave handles node pair (2p, 2p+1)
        int dlA = 2 * p, dlB = dlA + 1;
        int dA = nb0 + dlA;
        bool hasB = dlB < nloc;
        int dB = hasB ? nb0 + dlB : dA;
        float diA = dinv[dA], diB = dinv[dB];
        float accA = bf2f(tf[(size_t)dA * DD]) * diA * diA + bb;
        float accB = hasB ? (bf2f(tf[(size_t)dB * DD]) * diB * diB + bb) : 0.f;
        int jA = srp[dlA] - ebase, jendA = srp[dlA + 1] - ebase;  // multiples of 8
        int jB = jendA, jendB = hasB ? (srp[dlB + 1] - ebase) : jendA;

        if (staged) {
            for (; jA < jendA && jB < jendB; jA += 8, jB += 8)
                batch8x2(se, jA, jB, tbase, f2, accA, accB);
            for (; jA < jendA; jA += 8) batch8(se, jA, tbase, f2, accA);
            for (; jB < jendB; jB += 8) batch8(se, jB, tbase, f2, accB);
        } else {  // overflow block (vanishingly rare): csw from global
            const int2* ep = csw + ebase;
            for (; jA < jendA && jB < jendB; jA += 8, jB += 8)
                batch8x2(ep, jA, jB, tbase, f2, accA, accB);
            for (; jA < jendA; jA += 8) batch8(ep, jA, tbase, f2, accA);
            for (; jB < jendB; jB += 8) batch8(ep, jB, tbase, f2, accB);
        }
        h[(size_t)dA * DD + f] = accA;
        sum += accA;
        sq += accA * accA;
        if (hasB) {
            h[(size_t)dB * DD + f] = accB;
            sum += accB;
            sq += accB * accB;
        }
    }
    s_sum[threadIdx.x] = sum;
    s_sq[threadIdx.x] = sq;
    __syncthreads();
    if (threadIdx.x < 64) {
        sum = s_sum[f] + s_sum[64 + f] + s_sum[128 + f] + s_sum[192 + f];
        sq = s_sq[f] + s_sq[64 + f] + s_sq[128 + f] + s_sq[192 + f];
        atomicAdd(&accum_l[f], sum);
        atomicAdd(&accum_l[64 + f], sq);
    }
}

// ---------------- pool: inline BN finalize(layer3) + ReLU + mean-pool + counts ----------------
#define POOL_CHUNK 128
__global__ __launch_bounds__(256) void pool_kernel(const float* __restrict__ hraw,
                                                   const float* __restrict__ accum_l,
                                                   const float* __restrict__ gamma,
                                                   const float* __restrict__ beta,
                                                   const int* __restrict__ batch,
                                                   const int* __restrict__ flags,
                                                   float* __restrict__ pool,
                                                   float* __restrict__ counts) {
    __shared__ float ssc[64], ssh[64];
    if (threadIdx.x < 64) {
        float S = accum_l[threadIdx.x], Q = accum_l[64 + threadIdx.x];
        float mean = S / (float)NN;
        float var = fmaxf(Q / (float)NN - mean * mean, 0.f);
        float sc = gamma[threadIdx.x] * rsqrtf(var + BN_EPS);
        ssc[threadIdx.x] = sc;
        ssh[threadIdx.x] = beta[threadIdx.x] - mean * sc;
    }
    __syncthreads();
    int is32 = flags[1];
    int f = threadIdx.x & 63, rg = threadIdx.x >> 6;
    float sc = ssc[f], sh = ssh[f];
    int base = blockIdx.x * POOL_CHUNK;
    float acc = 0.f, cnt = 0.f;
    int cur = -1;
    for (int i = rg; i < POOL_CHUNK; i += 4) {
        int n = base + i;
        if (n >= NN) break;
        int g = ld_batch(batch, n, is32);
        if (g != cur) {
            if (cur >= 0) {
                atomicAdd(&pool[cur * DD + f], acc);
                if (f == 0) atomicAdd(&counts[cur], cnt);
            }
            acc = 0.f;
            cnt = 0.f;
            cur = g;
        }
        acc += fmaxf(hraw[(size_t)n * DD + f] * sc + sh, 0.f);
        cnt += 1.f;
    }
    if (cur >= 0) {
        atomicAdd(&pool[cur * DD + f], acc);
        if (f == 0) atomicAdd(&counts[cur], cnt);
    }
}

__global__ __launch_bounds__(256) void final_kernel(const float* __restrict__ pool,
                                                    const float* __restrict__ counts,
                                                    float* __restrict__ out) {
    int i = blockIdx.x * 256 + threadIdx.x;
    if (i < NG * DD) {
        int g = i >> 6;
        out[i] = pool[i] / fmaxf(counts[g], 1.0f);
    }
}

extern "C" void kernel_launch(void* const* d_in, const int* in_sizes, int n_in,
                              void* d_out, int out_size, void* d_ws, size_t ws_size,
                              hipStream_t stream) {
    const float* x = (const float*)d_in[0];       // [NN, DD] f32
    const int* edge_index = (const int*)d_in[1];  // [2, NE] int (width detected)
    const int* batch = (const int*)d_in[2];       // [NN] int (width detected)
    const float* Ws = (const float*)d_in[3];      // [3,64,64]
    const float* bs = (const float*)d_in[4];      // [3,64]
    const float* gammas = (const float*)d_in[5];  // [3,64]
    const float* betas = (const float*)d_in[6];   // [3,64]
    float* out = (float*)d_out;                   // [NG, DD]

    // workspace layout (deg_cnt/pool/counts contiguous -> single memset)
    float* h = (float*)d_ws;                    // 6,400,000 f
    bf16* t = (bf16*)(h + (size_t)NN * DD);     // 6,400,000 bf16 (12.8 MB)
    int2* csw = (int2*)(t + (size_t)NN * DD);   // CSW_CAP int2 (18.4 MB, padded CSR)
    float* dinv = (float*)(csw + CSW_CAP);      // 100,000 f
    int* deg_cnt = (int*)(dinv + NN);           // 100,000 i (also fill cursor)
    float* pool = (float*)(deg_cnt + NN);       // 8192 f
    float* counts = pool + NG * DD;             // 128 f
    int* rowptr = (int*)(counts + NG);          // 100,001 i (padded CSR offsets)
    float* accum = (float*)(rowptr + NN + 1);   // NL*128 f (BN sum/sumsq per layer)
    int* flags = (int*)(accum + NL * 128);      // 2 i
    int* blocksum = flags + 2;                  // 128 i

    // one memset: deg_cnt + pool + counts; one for padded csw (pad slots -> w=0)
    hipMemsetAsync(deg_cnt, 0, (NN + NG * DD + NG) * sizeof(float), stream);
    hipMemsetAsync(csw, 0, (size_t)CSW_CAP * sizeof(int2), stream);

    detect_kernel<<<1, 256, 0, stream>>>(edge_index, batch, flags);
    deg_kernel<<<(NE + 255) / 256, 256, 0, stream>>>(edge_index, flags, deg_cnt);
    scan_part_kernel<<<SCAN_BLK, 256, 0, stream>>>(deg_cnt, blocksum, dinv);
    scan_write_kernel<<<SCAN_BLK, 256, 0, stream>>>(deg_cnt, blocksum, rowptr);
    fill_kernel<<<(NE + 255) / 256, 256, 0, stream>>>(edge_index, flags, dinv, rowptr,
                                                      deg_cnt, csw);

    for (int l = 0; l < NL; ++l) {
        const float* hin = (l == 0) ? x : h;
        float alpha = (l == 0) ? 1.0f : 0.0f;  // identity vs ReLU on input transform
        gemm_kernel<<<NT, 256, 0, stream>>>(hin, Ws + (size_t)l * DD * DD,
                                            accum + (l - 1 >= 0 ? l - 1 : 0) * 128,
                                            gammas + (l - 1 >= 0 ? l - 1 : 0) * DD,
                                            betas + (l - 1 >= 0 ? l - 1 : 0) * DD,
                                            (l > 0) ? 1 : 0, alpha, t, accum + l * 128);
        gather_kernel<<<GB_BLOCKS, 256, 0, stream>>>(t, dinv, bs + l * DD, rowptr, csw, h,
                                                     accum + l * 128);
    }

    pool_kernel<<<(NN + POOL_CHUNK - 1) / POOL_CHUNK, 256, 0, stream>>>(
        h, accum + 2 * 128, gammas + 2 * DD, betas + 2 * DD, batch, flags, pool, counts);
    final_kernel<<<(NG * DD + 255) / 256, 256, 0, stream>>>(pool, counts, out);
}